// Round 4
// baseline (622.551 us; speedup 1.0000x reference)
//
#include <hip/hip_runtime.h>

typedef _Float16 hh;
typedef _Float16 h2  __attribute__((ext_vector_type(2)));
typedef _Float16 v4h __attribute__((ext_vector_type(4)));
typedef _Float16 v8h __attribute__((ext_vector_type(8)));
typedef float v4f    __attribute__((ext_vector_type(4)));
typedef unsigned short u16;

#define T_STEPS 36
#define FEAT 9
#define HID 64
#define BT 16
// sIn row (halves, stride 232 = 116 words):
//   parity0 block @0:   [c_c 0..8 | m 9..17 | h 18..81 | 1 @82 | 0 @83..95]
//   parity1 block @96:  same layout +96 (bias one @178)
//   dA @192..200 | 0 @201 | dB @202..210 | 0 @211 | 1 @212 | 0 @213..231
#define SIN_STR 232
// packed per-element row (halves): x 0..8 | m 9..17 | xh 18..26 | d 27..35 | pad
#define PK_STR 40

__device__ __forceinline__ float fast_exp2(float x) {
#if __has_builtin(__builtin_amdgcn_exp2f)
  return __builtin_amdgcn_exp2f(x);
#else
  return exp2f(x);
#endif
}
__device__ __forceinline__ float fast_rcp(float x) {
#if __has_builtin(__builtin_amdgcn_rcpf)
  return __builtin_amdgcn_rcpf(x);
#else
  return 1.f / x;
#endif
}
__device__ __forceinline__ float sigmoid_fast(float x) {
  return fast_rcp(1.f + fast_exp2(x * -1.442695041f));
}
__device__ __forceinline__ float tanh_fast(float x) {
  return 1.f - 2.f * fast_rcp(1.f + fast_exp2(x * 2.885390082f));
}
__device__ __forceinline__ float fdot2(h2 a, h2 b, float c) {
#if __has_builtin(__builtin_amdgcn_fdot2)
  return __builtin_amdgcn_fdot2(a, b, c, false);
#else
  return c + (float)a[0] * (float)b[0] + (float)a[1] * (float)b[1];
#endif
}
__device__ __forceinline__ h2 mkh2(hh a, hh b) { h2 r; r[0] = a; r[1] = b; return r; }
__device__ __forceinline__ v4f mfma16(v8h a, v8h b, v4f c) {
  return __builtin_amdgcn_mfma_f32_16x16x32_f16(a, b, c, 0, 0, 0);
}

// ---------------- kernel 0: zero ws denom slots + loss slot ----------------
__global__ void zero_ws(float* __restrict__ ws, float* __restrict__ out) {
  int tid = threadIdx.x;
  if (tid < T_STEPS) ws[tid] = 0.f;
  if (tid == 0) out[0] = 0.f;
}

// ---- kernel 1: denom[t] = sum over (B,F) of masks[:,t,:] ------------------
// One thread per batch element (contiguous 1296 B row), 36 STATIC-index
// accumulators (runtime indexing would spill to scratch — round-3 bug),
// wave-shuffle reduce per t, one global atomic per (block, t).
__global__ __launch_bounds__(64) void denom_kernel(const float* __restrict__ masks,
                                                   float* __restrict__ ws) {
  const int tid = threadIdx.x;
  const size_t e = (size_t)blockIdx.x * 64 + tid;
  const float4* p = (const float4*)masks + e * 81;  // 324 floats per element
  float acc[T_STEPS];
#pragma unroll
  for (int t = 0; t < T_STEPS; ++t) acc[t] = 0.f;
#pragma unroll
  for (int c = 0; c < 81; ++c) {
    float4 v = p[c];
    acc[(4 * c) / 9]     += v.x;
    acc[(4 * c + 1) / 9] += v.y;
    acc[(4 * c + 2) / 9] += v.z;
    acc[(4 * c + 3) / 9] += v.w;
  }
#pragma unroll
  for (int t = 0; t < T_STEPS; ++t) {
    float v = acc[t];
#pragma unroll
    for (int s = 32; s > 0; s >>= 1) v += __shfl_down(v, s, 64);
    if (tid == 0) atomicAdd(&ws[t], v);
  }
}

// ---------------- kernel 2: the full RITS scan -----------------------------
__global__ __launch_bounds__(256, 4) void rits_kernel(
    const float* __restrict__ values, const float* __restrict__ masks,
    const float* __restrict__ deltas,
    const float* __restrict__ W_gh, const float* __restrict__ b_gh,
    const float* __restrict__ W_gx, const float* __restrict__ b_gx,
    const float* __restrict__ W_hist, const float* __restrict__ b_hist,
    const float* __restrict__ W_feat, const float* __restrict__ b_feat,
    const float* __restrict__ W_comb, const float* __restrict__ b_comb,
    const float* __restrict__ W_ih, const float* __restrict__ W_hh,
    const float* __restrict__ b_ih, const float* __restrict__ b_hh,
    const float* __restrict__ denom, float* __restrict__ out) {

  __shared__ __align__(16) hh sIn[BT * SIN_STR];   // 7424 B
  __shared__ __align__(16) hh sPk[BT * PK_STR];    // 1280 B
  __shared__ float sRedW[4];

  const int tid = threadIdx.x;
  const int lane = tid & 63;
  const int wid = tid >> 6;
  const int q = lane >> 4;
  const int nlo = lane & 15;
  const int b0 = blockIdx.x * BT;
  const int j_col = 16 * wid + nlo;

  // ---- persistent register B-fragments (k = q*8+jj within a 32-K window) ----
  v8h bG[4][3];        // gates: k 0..17 Wih, 18..81 Whh, 82 bias
#pragma unroll
  for (int p = 0; p < 4; ++p)
#pragma unroll
    for (int kt = 0; kt < 3; ++kt) {
      int n = 64 * p + j_col;
      v8h r;
#pragma unroll
      for (int jj = 0; jj < 8; ++jj) {
        int k = kt * 32 + q * 8 + jj;
        float v = 0.f;
        if (k < 18)       v = W_ih[n * 18 + k];
        else if (k < 82)  v = W_hh[n * 64 + (k - 18)];
        else if (k == 82) v = b_ih[n] + b_hh[n];
        r[jj] = (hh)v;
      }
      bG[p][kt] = r;
    }
  v8h bH[3];           // x_h: cols nlo<9, k 18..81 Whist, 82 bias (used by wave 0 only)
#pragma unroll
  for (int kt = 0; kt < 3; ++kt) {
    v8h r;
#pragma unroll
    for (int jj = 0; jj < 8; ++jj) {
      int k = kt * 32 + q * 8 + jj;
      float v = 0.f;
      if (nlo < 9) {
        if (k >= 18 && k < 82) v = W_hist[nlo * 64 + (k - 18)];
        else if (k == 82)      v = b_hist[nlo];
      }
      r[jj] = (hh)v;
    }
    bH[kt] = r;
  }
  // gamma_h windows: A @176 (k2='1'@178 -> b_gh, k16..24 = dA); B @200 (k2..10 = dB, k12='1'@212)
  v8h bGamA, bGamB;
  {
    int n = j_col;
    v8h ra, rb;
#pragma unroll
    for (int jj = 0; jj < 8; ++jj) {
      int k = q * 8 + jj;
      float va = 0.f, vb = 0.f;
      if (k == 2) va = b_gh[n];
      else if (k >= 16 && k < 25) va = W_gh[n * 9 + (k - 16)];
      if (k >= 2 && k < 11) vb = W_gh[n * 9 + (k - 2)];
      else if (k == 12) vb = b_gh[n];
      ra[jj] = (hh)va; rb[jj] = (hh)vb;
    }
    bGamA = ra; bGamB = rb;
  }

  // ---- per-lane P2 weights (row fqw baked into registers; identical in both pairs) ----
  const int uP = tid & 127;
  const int eP = uP >> 3, fqw = uP & 7;
  const int myPair = wid >> 1;
  h2 wf1[5], wf2[5], wc1[9], wc2[9];
  float bf1 = b_feat[fqw], bf2 = b_feat[8];
  float bc1v = b_comb[fqw], bc2v = b_comb[8];
#pragma unroll
  for (int j = 0; j < 5; ++j) {
    int i0 = 2 * j, i1 = 2 * j + 1;
    hh a0 = (hh)((i0 == fqw) ? 0.f : W_feat[fqw * 9 + i0]);
    hh a1 = (hh)((i1 < 9) ? ((i1 == fqw) ? 0.f : W_feat[fqw * 9 + i1]) : 0.f);
    wf1[j] = mkh2(a0, a1);
    hh c0 = (hh)((i0 == 8) ? 0.f : W_feat[8 * 9 + i0]);
    hh c1 = (hh)((i1 < 9) ? W_feat[8 * 9 + i1] : 0.f);
    wf2[j] = mkh2(c0, c1);
  }
#pragma unroll
  for (int j = 0; j < 9; ++j) {
    wc1[j] = mkh2((hh)W_comb[fqw * 18 + 2 * j], (hh)W_comb[fqw * 18 + 2 * j + 1]);
    wc2[j] = mkh2((hh)W_comb[8 * 18 + 2 * j], (hh)W_comb[8 * 18 + 2 * j + 1]);
  }
  float wgx[9], bgxv[9];
#pragma unroll
  for (int f = 0; f < 9; ++f) { wgx[f] = W_gx[f * 9 + f]; bgxv[f] = b_gx[f]; }

  float* const outp0 = out + 1 + (size_t)(b0 + eP) * (T_STEPS * FEAT) + fqw;
  float* const outp8 = out + 1 + (size_t)(b0 + eP) * (T_STEPS * FEAT) + 8;

  // ---- LDS init ----
  for (int i = tid; i < BT * SIN_STR; i += 256) sIn[i] = (hh)0.f;
  __syncthreads();
  if (tid < BT) {
    sIn[tid * SIN_STR + 82] = (hh)1.f;
    sIn[tid * SIN_STR + 178] = (hh)1.f;
    sIn[tid * SIN_STR + 212] = (hh)1.f;
  }
  const int e1 = tid / 9, f1 = tid - 9 * e1;
  const bool pf = (tid < BT * FEAT);   // 144 prefetch lanes
  float dreg = 0.f;                    // holds d(t+1) for the sPk commit
  if (pf) {
    size_t off = (size_t)(b0 + e1) * (T_STEPS * FEAT) + f1;
    sPk[e1 * PK_STR + f1] = (hh)values[off];
    sPk[e1 * PK_STR + 9 + f1] = (hh)masks[off];
    sPk[e1 * PK_STR + 27 + f1] = (hh)deltas[off];
    float d1 = deltas[off + FEAT];
    dreg = d1;
    sIn[e1 * SIN_STR + 202 + f1] = (hh)d1;    // d(1) -> dB (parity 1)
  }
  __syncthreads();

  float c_s[4];
#pragma unroll
  for (int i = 0; i < 4; ++i) c_s[i] = 0.f;
  float loss_acc = 0.f;

  for (int t = 0; t < T_STEPS; ++t) {
    const float inv_den = fast_rcp(denom[t] + 1e-5f);

    // ==== P1: gamma(t+1)-arg MFMA (all waves, own cols) + x_h MFMA (wave 0) ====
    v4f gacc;
    {
      const int sel = (t + 1) & 1;
      const int awin = 176 + sel * 24;
      v8h a = *(const v8h*)&sIn[nlo * SIN_STR + awin + q * 8];
      v4f z4 = {0.f, 0.f, 0.f, 0.f};
      gacc = sel ? mfma16(a, bGamB, z4) : mfma16(a, bGamA, z4);
    }
    if (wid == 0) {
      const int base = (t & 1) * 96;
      v4f acc = {0.f, 0.f, 0.f, 0.f};
#pragma unroll
      for (int kt = 0; kt < 3; ++kt) {
        v8h a = *(const v8h*)&sIn[nlo * SIN_STR + base + kt * 32 + q * 8];
        acc = mfma16(a, bH[kt], acc);
      }
      if (nlo < 9) {
#pragma unroll
        for (int r = 0; r < 4; ++r)
          sPk[(q * 4 + r) * PK_STR + 18 + nlo] = (hh)acc[r];
      }
    }
    __syncthreads();

    // ==== P2 (alternating wave pair): x_c, gamma_x, z, alpha, c_h, c_c, loss ====
    if (myPair == (t & 1)) {
      const int pk = eP * PK_STR;
      float x_f  = (float)sPk[pk + fqw];
      float m_f  = (float)sPk[pk + 9 + fqw];
      float xh_f = (float)sPk[pk + 18 + fqw];
      v8h r0 = *(const v8h*)&sPk[pk];
      v8h r1 = *(const v8h*)&sPk[pk + 8];
      v8h r2 = *(const v8h*)&sPk[pk + 16];
      v8h r3 = *(const v8h*)&sPk[pk + 24];
      v4h r4 = *(const v4h*)&sPk[pk + 32];
      hh xxh[9] = {r0[0],r0[1],r0[2],r0[3],r0[4],r0[5],r0[6],r0[7],r1[0]};
      hh mmh[9] = {r1[1],r1[2],r1[3],r1[4],r1[5],r1[6],r1[7],r2[0],r2[1]};
      hh xhh[9] = {r2[2],r2[3],r2[4],r2[5],r2[6],r2[7],r3[0],r3[1],r3[2]};
      hh ddh[9] = {r3[3],r3[4],r3[5],r3[6],r3[7],r4[0],r4[1],r4[2],r4[3]};
      hh xch[10];
#pragma unroll
      for (int f = 0; f < 9; ++f) {
        u16 mb = __builtin_bit_cast(u16, mmh[f]);
        xch[f] = mb ? xxh[f] : xhh[f];     // masks are exactly 0.0/1.0
      }
      xch[9] = (hh)0.f;
      hh gxh[9];
#pragma unroll
      for (int f = 0; f < 9; ++f) {
        float y = fmaxf((float)ddh[f] * wgx[f] + bgxv[f], 0.f);
        gxh[f] = (hh)fast_exp2(y * -1.442695041f);
      }
      h2 xc2[5] = {mkh2(xch[0],xch[1]), mkh2(xch[2],xch[3]), mkh2(xch[4],xch[5]),
                   mkh2(xch[6],xch[7]), mkh2(xch[8],xch[9])};
      h2 g2[9]  = {mkh2(gxh[0],gxh[1]), mkh2(gxh[2],gxh[3]), mkh2(gxh[4],gxh[5]),
                   mkh2(gxh[6],gxh[7]), mkh2(gxh[8],mmh[0]), mkh2(mmh[1],mmh[2]),
                   mkh2(mmh[3],mmh[4]), mkh2(mmh[5],mmh[6]), mkh2(mmh[7],mmh[8])};
      float z1 = bf1, a1 = bc1v;
#pragma unroll
      for (int j = 0; j < 5; ++j) z1 = fdot2(wf1[j], xc2[j], z1);
#pragma unroll
      for (int j = 0; j < 9; ++j) a1 = fdot2(wc1[j], g2[j], a1);
      float ch1 = xh_f + a1 * (z1 - xh_f);
      bool obs1 = (m_f != 0.f);
      float cc1 = obs1 ? x_f : ch1;
      float lterm = obs1 ? (fabsf(x_f - xh_f) + fabsf(x_f - z1) + fabsf(x_f - ch1)) : 0.f;
      const int pb = (t & 1) * 96;
      sIn[eP * SIN_STR + pb + fqw] = (hh)cc1;
      sIn[eP * SIN_STR + pb + 9 + fqw] = (hh)m_f;
      outp0[t * FEAT] = cc1;
      if (fqw == 7) {
        float z2 = bf2, a2 = bc2v;
#pragma unroll
        for (int j = 0; j < 5; ++j) z2 = fdot2(wf2[j], xc2[j], z2);
#pragma unroll
        for (int j = 0; j < 9; ++j) a2 = fdot2(wc2[j], g2[j], a2);
        float x8 = (float)xxh[8], m8 = (float)mmh[8], xh8 = (float)xhh[8];
        float ch2 = xh8 + a2 * (z2 - xh8);
        bool obs2 = (m8 != 0.f);
        float cc2 = obs2 ? x8 : ch2;
        lterm += obs2 ? (fabsf(x8 - xh8) + fabsf(x8 - z2) + fabsf(x8 - ch2)) : 0.f;
        sIn[eP * SIN_STR + pb + 8] = (hh)cc2;
        sIn[eP * SIN_STR + pb + 17] = mmh[8];
        outp8[t * FEAT] = cc2;
      }
      loss_acc += lterm * inv_den;
    }
    __syncthreads();

    // ==== P3: gates MFMA, LSTM pointwise, decay+publish h(t+1), prefetch ====
    {
      float px = 0.f, pm = 0.f, pd = 0.f;
      const bool pre1 = pf && (t + 1 < T_STEPS);
      const bool pre2 = pf && (t + 2 < T_STEPS);
      if (pre1) {
        size_t off = (size_t)(b0 + e1) * (T_STEPS * FEAT) + (t + 1) * FEAT + f1;
        px = values[off]; pm = masks[off];
      }
      if (pre2) {
        size_t offd = (size_t)(b0 + e1) * (T_STEPS * FEAT) + (t + 2) * FEAT + f1;
        pd = deltas[offd];
      }

      const int base = (t & 1) * 96;
      const int pub = ((t + 1) & 1) * 96;
      v8h af[3];
#pragma unroll
      for (int kt = 0; kt < 3; ++kt)
        af[kt] = *(const v8h*)&sIn[nlo * SIN_STR + base + kt * 32 + q * 8];

      v4f acc[4];
#pragma unroll
      for (int p = 0; p < 4; ++p) acc[p] = (v4f){0.f, 0.f, 0.f, 0.f};
#pragma unroll
      for (int p = 0; p < 4; ++p)
#pragma unroll
        for (int kt = 0; kt < 3; ++kt)
          acc[p] = mfma16(af[kt], bG[p][kt], acc[p]);

#pragma unroll
      for (int r = 0; r < 4; ++r) {
        float ig = sigmoid_fast(acc[0][r]);
        float fg = sigmoid_fast(acc[1][r]);
        float gg = tanh_fast(acc[2][r]);
        float og = sigmoid_fast(acc[3][r]);
        float cn = fg * c_s[r] + ig * gg;
        c_s[r] = cn;
        float hn = og * tanh_fast(cn);
        float gam = fast_exp2(fmaxf(gacc[r], 0.f) * -1.442695041f);
        sIn[(q * 4 + r) * SIN_STR + pub + 18 + j_col] = (hh)(hn * gam);
      }

      if (pre1) {
        sPk[e1 * PK_STR + f1] = (hh)px;
        sPk[e1 * PK_STR + 9 + f1] = (hh)pm;
        sPk[e1 * PK_STR + 27 + f1] = (hh)dreg;
      }
      if (pre2) {
        const int sb = 192 + (t & 1) * 10;    // parity(t+2) d-slot
        sIn[e1 * SIN_STR + sb + f1] = (hh)pd;
        dreg = pd;
      }
    }
    __syncthreads();
  }

  // ---- loss reduction: wave shuffle -> LDS -> one atomic per block ----
  {
    float v = loss_acc;
#pragma unroll
    for (int s = 32; s > 0; s >>= 1) v += __shfl_down(v, s, 64);
    if (lane == 0) sRedW[wid] = v;
    __syncthreads();
    if (tid == 0)
      atomicAdd(out, (sRedW[0] + sRedW[1] + sRedW[2] + sRedW[3]) * (1.f / (float)T_STEPS));
  }
}

extern "C" void kernel_launch(void* const* d_in, const int* in_sizes, int n_in,
                              void* d_out, int out_size, void* d_ws, size_t ws_size,
                              hipStream_t stream) {
  const float* values = (const float*)d_in[0];
  const float* masks  = (const float*)d_in[1];
  const float* deltas = (const float*)d_in[2];
  const float* W_gh   = (const float*)d_in[3];
  const float* b_gh   = (const float*)d_in[4];
  const float* W_gx   = (const float*)d_in[5];
  const float* b_gx   = (const float*)d_in[6];
  const float* W_hist = (const float*)d_in[7];
  const float* b_hist = (const float*)d_in[8];
  const float* W_feat = (const float*)d_in[9];
  const float* b_feat = (const float*)d_in[10];
  const float* W_comb = (const float*)d_in[11];
  const float* b_comb = (const float*)d_in[12];
  const float* W_ih   = (const float*)d_in[13];
  const float* W_hh   = (const float*)d_in[14];
  const float* b_ih   = (const float*)d_in[15];
  const float* b_hh   = (const float*)d_in[16];

  float* out = (float*)d_out;
  float* ws  = (float*)d_ws;
  int B = in_sizes[0] / (T_STEPS * FEAT);

  zero_ws<<<1, 64, 0, stream>>>(ws, out);
  denom_kernel<<<B / 64, 64, 0, stream>>>(masks, ws);
  rits_kernel<<<B / BT, 256, 0, stream>>>(values, masks, deltas,
                                          W_gh, b_gh, W_gx, b_gx,
                                          W_hist, b_hist, W_feat, b_feat,
                                          W_comb, b_comb, W_ih, W_hh,
                                          b_ih, b_hh, ws, out);
}

// Round 5
// 306.158 us; speedup vs baseline: 2.0334x; 2.0334x over previous
//
#include <hip/hip_runtime.h>

typedef _Float16 hh;
typedef _Float16 h2  __attribute__((ext_vector_type(2)));
typedef _Float16 v4h __attribute__((ext_vector_type(4)));
typedef _Float16 v8h __attribute__((ext_vector_type(8)));
typedef float v4f    __attribute__((ext_vector_type(4)));
typedef unsigned short u16;

#define T_STEPS 36
#define FEAT 9
#define HID 64
#define BT 16
// sIn row (halves, stride 232 = 116 words):
//   parity0 block @0:   [c_c 0..8 | m 9..17 | h 18..81 | 1 @82 | 0 @83..95]
//   parity1 block @96:  same layout +96 (bias one @178)
//   dA @192..200 | 0 @201 | dB @202..210 | 0 @211 | 1 @212 | 0 @213..231
#define SIN_STR 232
// packed per-element row (halves): x 0..8 | m 9..17 | xh 18..26 | d 27..35 | pad
#define PK_STR 40

__device__ __forceinline__ float fast_exp2(float x) {
#if __has_builtin(__builtin_amdgcn_exp2f)
  return __builtin_amdgcn_exp2f(x);
#else
  return exp2f(x);
#endif
}
__device__ __forceinline__ float fast_rcp(float x) {
#if __has_builtin(__builtin_amdgcn_rcpf)
  return __builtin_amdgcn_rcpf(x);
#else
  return 1.f / x;
#endif
}
__device__ __forceinline__ float sigmoid_fast(float x) {
  return fast_rcp(1.f + fast_exp2(x * -1.442695041f));
}
__device__ __forceinline__ float tanh_fast(float x) {
  return 1.f - 2.f * fast_rcp(1.f + fast_exp2(x * 2.885390082f));
}
__device__ __forceinline__ float fdot2(h2 a, h2 b, float c) {
#if __has_builtin(__builtin_amdgcn_fdot2)
  return __builtin_amdgcn_fdot2(a, b, c, false);
#else
  return c + (float)a[0] * (float)b[0] + (float)a[1] * (float)b[1];
#endif
}
__device__ __forceinline__ h2 mkh2(hh a, hh b) { h2 r; r[0] = a; r[1] = b; return r; }
__device__ __forceinline__ v4f mfma16(v8h a, v8h b, v4f c) {
  return __builtin_amdgcn_mfma_f32_16x16x32_f16(a, b, c, 0, 0, 0);
}

// ---------------- kernel 0: zero ws denom slots + loss slot ----------------
__global__ void zero_ws(float* __restrict__ ws, float* __restrict__ out) {
  int tid = threadIdx.x;
  if (tid < T_STEPS) ws[tid] = 0.f;
  if (tid == 0) out[0] = 0.f;
}

// ---- kernel 1: denom[t] = sum over (B,F) of masks[:,t,:] ------------------
// 256-thread blocks; the block's 4 waves each process a STATIC quarter of the
// 81-float4 row for the same 64 elements (static c -> static acc indices ->
// no scratch spill, the round-3/4 bug). Shuffle-reduce per t, cross-wave via
// LDS, 36 atomics per block.
__global__ __launch_bounds__(256) void denom_kernel(const float* __restrict__ masks,
                                                    float* __restrict__ ws) {
  __shared__ float sW[4][T_STEPS];
  const int tid = threadIdx.x;
  const int lane = tid & 63;
  const int wid = tid >> 6;                 // quarter selector (wave-uniform)
  const size_t e = (size_t)blockIdx.x * 64 + lane;
  const float4* p = (const float4*)masks + e * 81;  // 324 floats per element
  float acc[T_STEPS];
#pragma unroll
  for (int t = 0; t < T_STEPS; ++t) acc[t] = 0.f;
  if (wid == 0) {
#pragma unroll
    for (int c = 0; c < 21; ++c) {
      float4 v = p[c];
      acc[(4 * c) / 9] += v.x; acc[(4 * c + 1) / 9] += v.y;
      acc[(4 * c + 2) / 9] += v.z; acc[(4 * c + 3) / 9] += v.w;
    }
  } else if (wid == 1) {
#pragma unroll
    for (int c = 21; c < 41; ++c) {
      float4 v = p[c];
      acc[(4 * c) / 9] += v.x; acc[(4 * c + 1) / 9] += v.y;
      acc[(4 * c + 2) / 9] += v.z; acc[(4 * c + 3) / 9] += v.w;
    }
  } else if (wid == 2) {
#pragma unroll
    for (int c = 41; c < 61; ++c) {
      float4 v = p[c];
      acc[(4 * c) / 9] += v.x; acc[(4 * c + 1) / 9] += v.y;
      acc[(4 * c + 2) / 9] += v.z; acc[(4 * c + 3) / 9] += v.w;
    }
  } else {
#pragma unroll
    for (int c = 61; c < 81; ++c) {
      float4 v = p[c];
      acc[(4 * c) / 9] += v.x; acc[(4 * c + 1) / 9] += v.y;
      acc[(4 * c + 2) / 9] += v.z; acc[(4 * c + 3) / 9] += v.w;
    }
  }
#pragma unroll
  for (int t = 0; t < T_STEPS; ++t) {
    float v = acc[t];
#pragma unroll
    for (int s = 32; s > 0; s >>= 1) v += __shfl_down(v, s, 64);
    if (lane == 0) sW[wid][t] = v;
  }
  __syncthreads();
  if (tid < T_STEPS)
    atomicAdd(&ws[tid], sW[0][tid] + sW[1][tid] + sW[2][tid] + sW[3][tid]);
}

// ---------------- kernel 2: the full RITS scan -----------------------------
// __launch_bounds__(256, 2): do NOT force 4 waves/EU — round-4 evidence:
// (256,4) capped VGPR at 128 < ~110-live set -> scratch spill, FETCH 401 MB,
// 434 us. Natural allocation (~105 VGPR) already permits 4 waves/SIMD.
__global__ __launch_bounds__(256, 2) void rits_kernel(
    const float* __restrict__ values, const float* __restrict__ masks,
    const float* __restrict__ deltas,
    const float* __restrict__ W_gh, const float* __restrict__ b_gh,
    const float* __restrict__ W_gx, const float* __restrict__ b_gx,
    const float* __restrict__ W_hist, const float* __restrict__ b_hist,
    const float* __restrict__ W_feat, const float* __restrict__ b_feat,
    const float* __restrict__ W_comb, const float* __restrict__ b_comb,
    const float* __restrict__ W_ih, const float* __restrict__ W_hh,
    const float* __restrict__ b_ih, const float* __restrict__ b_hh,
    const float* __restrict__ denom, float* __restrict__ out) {

  __shared__ __align__(16) hh sIn[BT * SIN_STR];   // 7424 B
  __shared__ __align__(16) hh sPk[BT * PK_STR];    // 1280 B
  __shared__ float sRedW[4];

  const int tid = threadIdx.x;
  const int lane = tid & 63;
  const int wid = tid >> 6;
  const int q = lane >> 4;
  const int nlo = lane & 15;
  const int b0 = blockIdx.x * BT;
  const int j_col = 16 * wid + nlo;

  // ---- persistent register B-fragments (k = q*8+jj within a 32-K window) ----
  v8h bG[4][3];        // gates: k 0..17 Wih, 18..81 Whh, 82 bias
#pragma unroll
  for (int p = 0; p < 4; ++p)
#pragma unroll
    for (int kt = 0; kt < 3; ++kt) {
      int n = 64 * p + j_col;
      v8h r;
#pragma unroll
      for (int jj = 0; jj < 8; ++jj) {
        int k = kt * 32 + q * 8 + jj;
        float v = 0.f;
        if (k < 18)       v = W_ih[n * 18 + k];
        else if (k < 82)  v = W_hh[n * 64 + (k - 18)];
        else if (k == 82) v = b_ih[n] + b_hh[n];
        r[jj] = (hh)v;
      }
      bG[p][kt] = r;
    }
  v8h bH[3];           // x_h: cols nlo<9, k 18..81 Whist, 82 bias (wave 0 only)
#pragma unroll
  for (int kt = 0; kt < 3; ++kt) {
    v8h r;
#pragma unroll
    for (int jj = 0; jj < 8; ++jj) {
      int k = kt * 32 + q * 8 + jj;
      float v = 0.f;
      if (nlo < 9) {
        if (k >= 18 && k < 82) v = W_hist[nlo * 64 + (k - 18)];
        else if (k == 82)      v = b_hist[nlo];
      }
      r[jj] = (hh)v;
    }
    bH[kt] = r;
  }
  // gamma_h windows: A @176 (k2='1'@178 -> b_gh, k16..24 = dA); B @200 (k2..10 = dB, k12='1'@212)
  v8h bGamA, bGamB;
  {
    int n = j_col;
    v8h ra, rb;
#pragma unroll
    for (int jj = 0; jj < 8; ++jj) {
      int k = q * 8 + jj;
      float va = 0.f, vb = 0.f;
      if (k == 2) va = b_gh[n];
      else if (k >= 16 && k < 25) va = W_gh[n * 9 + (k - 16)];
      if (k >= 2 && k < 11) vb = W_gh[n * 9 + (k - 2)];
      else if (k == 12) vb = b_gh[n];
      ra[jj] = (hh)va; rb[jj] = (hh)vb;
    }
    bGamA = ra; bGamB = rb;
  }

  // ---- per-lane P2 weights (row fqw baked into registers; same in both pairs) ----
  const int uP = tid & 127;
  const int eP = uP >> 3, fqw = uP & 7;
  const int myPair = wid >> 1;
  h2 wf1[5], wf2[5], wc1[9], wc2[9];
  float bf1 = b_feat[fqw], bf2 = b_feat[8];
  float bc1v = b_comb[fqw], bc2v = b_comb[8];
#pragma unroll
  for (int j = 0; j < 5; ++j) {
    int i0 = 2 * j, i1 = 2 * j + 1;
    hh a0 = (hh)((i0 == fqw) ? 0.f : W_feat[fqw * 9 + i0]);
    hh a1 = (hh)((i1 < 9) ? ((i1 == fqw) ? 0.f : W_feat[fqw * 9 + i1]) : 0.f);
    wf1[j] = mkh2(a0, a1);
    hh c0 = (hh)((i0 == 8) ? 0.f : W_feat[8 * 9 + i0]);
    hh c1 = (hh)((i1 < 9) ? W_feat[8 * 9 + i1] : 0.f);
    wf2[j] = mkh2(c0, c1);
  }
#pragma unroll
  for (int j = 0; j < 9; ++j) {
    wc1[j] = mkh2((hh)W_comb[fqw * 18 + 2 * j], (hh)W_comb[fqw * 18 + 2 * j + 1]);
    wc2[j] = mkh2((hh)W_comb[8 * 18 + 2 * j], (hh)W_comb[8 * 18 + 2 * j + 1]);
  }
  float wgx[9], bgxv[9];
#pragma unroll
  for (int f = 0; f < 9; ++f) { wgx[f] = W_gx[f * 9 + f]; bgxv[f] = b_gx[f]; }

  float* const outp0 = out + 1 + (size_t)(b0 + eP) * (T_STEPS * FEAT) + fqw;
  float* const outp8 = out + 1 + (size_t)(b0 + eP) * (T_STEPS * FEAT) + 8;

  // ---- LDS init ----
  for (int i = tid; i < BT * SIN_STR; i += 256) sIn[i] = (hh)0.f;
  __syncthreads();
  if (tid < BT) {
    sIn[tid * SIN_STR + 82] = (hh)1.f;
    sIn[tid * SIN_STR + 178] = (hh)1.f;
    sIn[tid * SIN_STR + 212] = (hh)1.f;
  }
  const int e1 = tid / 9, f1 = tid - 9 * e1;
  const bool pf = (tid < BT * FEAT);   // 144 prefetch lanes
  float dreg = 0.f;                    // holds d(t+1) for the sPk commit
  if (pf) {
    size_t off = (size_t)(b0 + e1) * (T_STEPS * FEAT) + f1;
    sPk[e1 * PK_STR + f1] = (hh)values[off];
    sPk[e1 * PK_STR + 9 + f1] = (hh)masks[off];
    sPk[e1 * PK_STR + 27 + f1] = (hh)deltas[off];
    float d1 = deltas[off + FEAT];
    dreg = d1;
    sIn[e1 * SIN_STR + 202 + f1] = (hh)d1;    // d(1) -> dB (parity 1)
  }
  __syncthreads();

  float c_s[4];
#pragma unroll
  for (int i = 0; i < 4; ++i) c_s[i] = 0.f;
  float loss_acc = 0.f;

  for (int t = 0; t < T_STEPS; ++t) {
    const float inv_den = fast_rcp(denom[t] + 1e-5f);

    // ==== P1: gamma(t+1)-arg MFMA (all waves, own cols) + x_h MFMA (wave 0) ====
    v4f gacc;
    {
      const int sel = (t + 1) & 1;
      const int awin = 176 + sel * 24;
      v8h a = *(const v8h*)&sIn[nlo * SIN_STR + awin + q * 8];
      v4f z4 = {0.f, 0.f, 0.f, 0.f};
      gacc = sel ? mfma16(a, bGamB, z4) : mfma16(a, bGamA, z4);
    }
    if (wid == 0) {
      const int base = (t & 1) * 96;
      v4f acc = {0.f, 0.f, 0.f, 0.f};
#pragma unroll
      for (int kt = 0; kt < 3; ++kt) {
        v8h a = *(const v8h*)&sIn[nlo * SIN_STR + base + kt * 32 + q * 8];
        acc = mfma16(a, bH[kt], acc);
      }
      if (nlo < 9) {
#pragma unroll
        for (int r = 0; r < 4; ++r)
          sPk[(q * 4 + r) * PK_STR + 18 + nlo] = (hh)acc[r];
      }
    }
    __syncthreads();

    // ==== P2 (alternating wave pair): x_c, gamma_x, z, alpha, c_h, c_c, loss ====
    if (myPair == (t & 1)) {
      const int pk = eP * PK_STR;
      float x_f  = (float)sPk[pk + fqw];
      float m_f  = (float)sPk[pk + 9 + fqw];
      float xh_f = (float)sPk[pk + 18 + fqw];
      v8h r0 = *(const v8h*)&sPk[pk];
      v8h r1 = *(const v8h*)&sPk[pk + 8];
      v8h r2 = *(const v8h*)&sPk[pk + 16];
      v8h r3 = *(const v8h*)&sPk[pk + 24];
      v4h r4 = *(const v4h*)&sPk[pk + 32];
      hh xxh[9] = {r0[0],r0[1],r0[2],r0[3],r0[4],r0[5],r0[6],r0[7],r1[0]};
      hh mmh[9] = {r1[1],r1[2],r1[3],r1[4],r1[5],r1[6],r1[7],r2[0],r2[1]};
      hh xhh[9] = {r2[2],r2[3],r2[4],r2[5],r2[6],r2[7],r3[0],r3[1],r3[2]};
      hh ddh[9] = {r3[3],r3[4],r3[5],r3[6],r3[7],r4[0],r4[1],r4[2],r4[3]};
      hh xch[10];
#pragma unroll
      for (int f = 0; f < 9; ++f) {
        u16 mb = __builtin_bit_cast(u16, mmh[f]);
        xch[f] = mb ? xxh[f] : xhh[f];     // masks are exactly 0.0/1.0
      }
      xch[9] = (hh)0.f;
      hh gxh[9];
#pragma unroll
      for (int f = 0; f < 9; ++f) {
        float y = fmaxf((float)ddh[f] * wgx[f] + bgxv[f], 0.f);
        gxh[f] = (hh)fast_exp2(y * -1.442695041f);
      }
      h2 xc2[5] = {mkh2(xch[0],xch[1]), mkh2(xch[2],xch[3]), mkh2(xch[4],xch[5]),
                   mkh2(xch[6],xch[7]), mkh2(xch[8],xch[9])};
      h2 g2[9]  = {mkh2(gxh[0],gxh[1]), mkh2(gxh[2],gxh[3]), mkh2(gxh[4],gxh[5]),
                   mkh2(gxh[6],gxh[7]), mkh2(gxh[8],mmh[0]), mkh2(mmh[1],mmh[2]),
                   mkh2(mmh[3],mmh[4]), mkh2(mmh[5],mmh[6]), mkh2(mmh[7],mmh[8])};
      float z1 = bf1, a1 = bc1v;
#pragma unroll
      for (int j = 0; j < 5; ++j) z1 = fdot2(wf1[j], xc2[j], z1);
#pragma unroll
      for (int j = 0; j < 9; ++j) a1 = fdot2(wc1[j], g2[j], a1);
      float ch1 = xh_f + a1 * (z1 - xh_f);
      bool obs1 = (m_f != 0.f);
      float cc1 = obs1 ? x_f : ch1;
      float lterm = obs1 ? (fabsf(x_f - xh_f) + fabsf(x_f - z1) + fabsf(x_f - ch1)) : 0.f;
      const int pb = (t & 1) * 96;
      sIn[eP * SIN_STR + pb + fqw] = (hh)cc1;
      sIn[eP * SIN_STR + pb + 9 + fqw] = (hh)m_f;
      outp0[t * FEAT] = cc1;
      if (fqw == 7) {
        float z2 = bf2, a2 = bc2v;
#pragma unroll
        for (int j = 0; j < 5; ++j) z2 = fdot2(wf2[j], xc2[j], z2);
#pragma unroll
        for (int j = 0; j < 9; ++j) a2 = fdot2(wc2[j], g2[j], a2);
        float x8 = (float)xxh[8], m8 = (float)mmh[8], xh8 = (float)xhh[8];
        float ch2 = xh8 + a2 * (z2 - xh8);
        bool obs2 = (m8 != 0.f);
        float cc2 = obs2 ? x8 : ch2;
        lterm += obs2 ? (fabsf(x8 - xh8) + fabsf(x8 - z2) + fabsf(x8 - ch2)) : 0.f;
        sIn[eP * SIN_STR + pb + 8] = (hh)cc2;
        sIn[eP * SIN_STR + pb + 17] = mmh[8];
        outp8[t * FEAT] = cc2;
      }
      loss_acc += lterm * inv_den;
    }
    __syncthreads();

    // ==== P3: gates MFMA, LSTM pointwise, decay+publish h(t+1), prefetch ====
    {
      float px = 0.f, pm = 0.f, pd = 0.f;
      const bool pre1 = pf && (t + 1 < T_STEPS);
      const bool pre2 = pf && (t + 2 < T_STEPS);
      if (pre1) {
        size_t off = (size_t)(b0 + e1) * (T_STEPS * FEAT) + (t + 1) * FEAT + f1;
        px = values[off]; pm = masks[off];
      }
      if (pre2) {
        size_t offd = (size_t)(b0 + e1) * (T_STEPS * FEAT) + (t + 2) * FEAT + f1;
        pd = deltas[offd];
      }

      const int base = (t & 1) * 96;
      const int pub = ((t + 1) & 1) * 96;
      v8h af[3];
#pragma unroll
      for (int kt = 0; kt < 3; ++kt)
        af[kt] = *(const v8h*)&sIn[nlo * SIN_STR + base + kt * 32 + q * 8];

      v4f acc[4];
#pragma unroll
      for (int p = 0; p < 4; ++p) acc[p] = (v4f){0.f, 0.f, 0.f, 0.f};
#pragma unroll
      for (int p = 0; p < 4; ++p)
#pragma unroll
        for (int kt = 0; kt < 3; ++kt)
          acc[p] = mfma16(af[kt], bG[p][kt], acc[p]);

#pragma unroll
      for (int r = 0; r < 4; ++r) {
        float ig = sigmoid_fast(acc[0][r]);
        float fg = sigmoid_fast(acc[1][r]);
        float gg = tanh_fast(acc[2][r]);
        float og = sigmoid_fast(acc[3][r]);
        float cn = fg * c_s[r] + ig * gg;
        c_s[r] = cn;
        float hn = og * tanh_fast(cn);
        float gam = fast_exp2(fmaxf(gacc[r], 0.f) * -1.442695041f);
        sIn[(q * 4 + r) * SIN_STR + pub + 18 + j_col] = (hh)(hn * gam);
      }

      if (pre1) {
        sPk[e1 * PK_STR + f1] = (hh)px;
        sPk[e1 * PK_STR + 9 + f1] = (hh)pm;
        sPk[e1 * PK_STR + 27 + f1] = (hh)dreg;
      }
      if (pre2) {
        const int sb = 192 + (t & 1) * 10;    // parity(t+2) d-slot
        sIn[e1 * SIN_STR + sb + f1] = (hh)pd;
        dreg = pd;
      }
    }
    __syncthreads();
  }

  // ---- loss reduction: wave shuffle -> LDS -> one atomic per block ----
  {
    float v = loss_acc;
#pragma unroll
    for (int s = 32; s > 0; s >>= 1) v += __shfl_down(v, s, 64);
    if (lane == 0) sRedW[wid] = v;
    __syncthreads();
    if (tid == 0)
      atomicAdd(out, (sRedW[0] + sRedW[1] + sRedW[2] + sRedW[3]) * (1.f / (float)T_STEPS));
  }
}

extern "C" void kernel_launch(void* const* d_in, const int* in_sizes, int n_in,
                              void* d_out, int out_size, void* d_ws, size_t ws_size,
                              hipStream_t stream) {
  const float* values = (const float*)d_in[0];
  const float* masks  = (const float*)d_in[1];
  const float* deltas = (const float*)d_in[2];
  const float* W_gh   = (const float*)d_in[3];
  const float* b_gh   = (const float*)d_in[4];
  const float* W_gx   = (const float*)d_in[5];
  const float* b_gx   = (const float*)d_in[6];
  const float* W_hist = (const float*)d_in[7];
  const float* b_hist = (const float*)d_in[8];
  const float* W_feat = (const float*)d_in[9];
  const float* b_feat = (const float*)d_in[10];
  const float* W_comb = (const float*)d_in[11];
  const float* b_comb = (const float*)d_in[12];
  const float* W_ih   = (const float*)d_in[13];
  const float* W_hh   = (const float*)d_in[14];
  const float* b_ih   = (const float*)d_in[15];
  const float* b_hh   = (const float*)d_in[16];

  float* out = (float*)d_out;
  float* ws  = (float*)d_ws;
  int B = in_sizes[0] / (T_STEPS * FEAT);

  zero_ws<<<1, 64, 0, stream>>>(ws, out);
  denom_kernel<<<B / 64, 256, 0, stream>>>(masks, ws);
  rits_kernel<<<B / BT, 256, 0, stream>>>(values, masks, deltas,
                                          W_gh, b_gh, W_gx, b_gx,
                                          W_hist, b_hist, W_feat, b_feat,
                                          W_comb, b_comb, W_ih, W_hh,
                                          b_ih, b_hh, ws, out);
}